// Round 5
// baseline (126.051 us; speedup 1.0000x reference)
//
#include <hip/hip_runtime.h>

// Causal dilated conv1d (dilation=64, K=2) + tanh*sigmoid gate via bf16 MFMA.
// Round 5: 2 tiles/block with circular 16KB LDS, 8 blocks/CU (100% occupancy),
// grid == resident set (no tail), single-bf16 w (error ~0.010 < 0.02 thr).
// y[b,co,t] = sum_ci w[co][ci][0]*x[b][ci][t-64] + w[co][ci][1]*x[b][ci][t]

#define B_ 16
#define C_ 64
#define T_ 16384
#define RR 128            // LDS rows (t), row = 64 bf16 = 128 B, 16 KiB total

typedef __attribute__((ext_vector_type(8))) short short8;
typedef __attribute__((ext_vector_type(4))) float f32x4;

union Frag { short8 s; unsigned u[4]; };

__device__ __forceinline__ unsigned pack_rne(float a, float b) {
    unsigned ua = __float_as_uint(a), ub = __float_as_uint(b);
    unsigned ra = ua + 0x7fffu + ((ua >> 16) & 1u);
    unsigned rb = ub + 0x7fffu + ((ub >> 16) & 1u);
    return (ra >> 16) | (rb & 0xffff0000u);
}

__global__ __launch_bounds__(256, 8) void conv_gate_mfma5(
    const float* __restrict__ x,
    const float* __restrict__ w,
    float* __restrict__ out)
{
    __shared__ unsigned short xs[RR * 64];   // 16384 B -> 8 blocks/CU

    const int tid  = threadIdx.x;
    const int lane = tid & 63;
    const int wid  = tid >> 6;
    const int m    = lane & 15;       // MFMA row (co) / D col participant
    const int q    = lane >> 4;
    const int n    = m;               // B-frag col = t offset within subtile

    // block -> (tile-pair, batch); XCD swizzle: consecutive pairs share an XCD
    const int bx  = blockIdx.x;                      // 0..127
    const int pr  = ((bx & 7) << 4) | (bx >> 3);     // swizzled pair index
    const int b   = blockIdx.y;
    const int t0b = pr * 128;                        // first output t of pair
    const float* xb = x + (size_t)b * C_ * T_;

    // ---- stage tile-0 rows: lds rr in [0,128) <- global t = t0b - 64 + rr
    #pragma unroll
    for (int it = 0; it < 4; ++it) {
        int task = it * 256 + tid;
        int rr   = task & 127;
        int c8   = task >> 7;             // 0..7
        int g    = t0b - 64 + rr;
        float v[8];
        if (g >= 0) {
            const float* xp = xb + (size_t)(8 * c8) * T_ + g;
            #pragma unroll
            for (int i = 0; i < 8; ++i) v[i] = xp[(size_t)i * T_];
        } else {
            #pragma unroll
            for (int i = 0; i < 8; ++i) v[i] = 0.f;
        }
        int so = rr * 64 + ((c8 ^ (rr & 7)) * 8);
        *(uint4*)(&xs[so]) = make_uint4(pack_rne(v[0], v[1]), pack_rne(v[2], v[3]),
                                        pack_rne(v[4], v[5]), pack_rne(v[6], v[7]));
    }

    // ---- w fragments (A-layout), single RNE bf16: co = 16*wid + m
    const int co = wid * 16 + m;
    Frag wh[2][2];   // [tap p][k-half h]
    #pragma unroll
    for (int h = 0; h < 2; ++h) {
        const float* wp = w + co * 128 + h * 64 + q * 16;
        float f[16];
        #pragma unroll
        for (int v4 = 0; v4 < 4; ++v4) {
            float4 t4 = *(const float4*)(wp + 4 * v4);
            f[4*v4+0] = t4.x; f[4*v4+1] = t4.y; f[4*v4+2] = t4.z; f[4*v4+3] = t4.w;
        }
        #pragma unroll
        for (int p = 0; p < 2; ++p)
            #pragma unroll
            for (int d = 0; d < 4; ++d)
                wh[p][h].u[d] = pack_rne(f[4*d + p], f[4*d + 2 + p]);
    }

    const int sw_base = n & 7;
    float* ob = out + ((size_t)b * C_ + wid * 16) * T_ + t0b;

    f32x4 acc[4];
    #pragma unroll
    for (int s = 0; s < 4; ++s) acc[s] = (f32x4){0.f, 0.f, 0.f, 0.f};

    __syncthreads();

    // ================= tile 0 compute =================
    #pragma unroll
    for (int u = 0; u < 8; ++u) {
        int lr    = 16 * u + n;            // lds row (== global row for tile 0)
        int rbase = lr * 64;
        int sw    = lr & 7;                // == sw_base here, but keep general
        Frag f0, f1;
        f0.s = *(const short8*)(&xs[rbase + ((q ^ sw) * 8)]);
        f1.s = *(const short8*)(&xs[rbase + (((4 + q) ^ sw) * 8)]);
        const int tap = u >> 2, s = u & 3;
        acc[s] = __builtin_amdgcn_mfma_f32_16x16x32_bf16(wh[tap][0].s, f0.s, acc[s], 0, 0, 0);
        acc[s] = __builtin_amdgcn_mfma_f32_16x16x32_bf16(wh[tap][1].s, f1.s, acc[s], 0, 0, 0);
    }

    __syncthreads();   // compute-0 done before overwriting lds rows [0,64)

    // ---- stage tile-1 new rows: lds rr2 in [0,64) <- global t = t0b + 64 + rr2
    #pragma unroll
    for (int it = 0; it < 2; ++it) {
        int task = it * 256 + tid;
        int rr2  = task & 63;              // == lane
        int c8   = task >> 6;              // it*4 + wid
        int g    = t0b + 64 + rr2;
        const float* xp = xb + (size_t)(8 * c8) * T_ + g;
        float v[8];
        #pragma unroll
        for (int i = 0; i < 8; ++i) v[i] = xp[(size_t)i * T_];
        int so = rr2 * 64 + ((c8 ^ (rr2 & 7)) * 8);
        *(uint4*)(&xs[so]) = make_uint4(pack_rne(v[0], v[1]), pack_rne(v[2], v[3]),
                                        pack_rne(v[4], v[5]), pack_rne(v[6], v[7]));
    }

    // ---- epilogue tile 0 (regs only — overlaps stage-1 load latency)
    #pragma unroll
    for (int s = 0; s < 4; ++s) {
        #pragma unroll
        for (int r = 0; r < 4; ++r) {
            float y = acc[s][r];
            y = fminf(fmaxf(y, -20.f), 20.f);
            float t  = __expf(-y);
            float o  = (1.f - t) * __builtin_amdgcn_rcpf(1.f + t * t);
            ob[(size_t)(4 * q + r) * T_ + 16 * s + n] = o;
        }
        acc[s] = (f32x4){0.f, 0.f, 0.f, 0.f};
    }

    __syncthreads();

    // ================= tile 1 compute =================
    #pragma unroll
    for (int u = 0; u < 8; ++u) {
        int gr    = 64 + 16 * u + n;       // global row within pair
        int lr    = gr & 127;              // circular lds row
        int rbase = lr * 64;
        int sw    = lr & 7;
        Frag f0, f1;
        f0.s = *(const short8*)(&xs[rbase + ((q ^ sw) * 8)]);
        f1.s = *(const short8*)(&xs[rbase + (((4 + q) ^ sw) * 8)]);
        const int tap = u >> 2, s = u & 3;
        acc[s] = __builtin_amdgcn_mfma_f32_16x16x32_bf16(wh[tap][0].s, f0.s, acc[s], 0, 0, 0);
        acc[s] = __builtin_amdgcn_mfma_f32_16x16x32_bf16(wh[tap][1].s, f1.s, acc[s], 0, 0, 0);
    }

    // ---- epilogue tile 1
    #pragma unroll
    for (int s = 0; s < 4; ++s) {
        #pragma unroll
        for (int r = 0; r < 4; ++r) {
            float y = acc[s][r];
            y = fminf(fmaxf(y, -20.f), 20.f);
            float t  = __expf(-y);
            float o  = (1.f - t) * __builtin_amdgcn_rcpf(1.f + t * t);
            ob[(size_t)(4 * q + r) * T_ + 64 + 16 * s + n] = o;
        }
    }
}

extern "C" void kernel_launch(void* const* d_in, const int* in_sizes, int n_in,
                              void* d_out, int out_size, void* d_ws, size_t ws_size,
                              hipStream_t stream) {
    const float* x = (const float*)d_in[0];
    const float* w = (const float*)d_in[1];
    float* out = (float*)d_out;
    dim3 grid(T_ / 128, B_);   // 128 tile-pairs x 16 batches = 2048 blocks
    conv_gate_mfma5<<<grid, dim3(256), 0, stream>>>(x, w, out);
}